// Round 11
// baseline (151.811 us; speedup 1.0000x reference)
//
#include <hip/hip_runtime.h>

#define IN_DIM  128

typedef __bf16 bf16x8 __attribute__((ext_vector_type(8)));
typedef float  f32x4  __attribute__((ext_vector_type(4)));

static inline size_t align256(size_t x) { return (x + 255) & ~size_t(255); }

// ---------- bf16 helpers (RNE) ----------
__device__ __forceinline__ ushort f2b1(float f) {
    union { float f; uint u; } c; c.f = f;
    uint u = c.u;
    uint r = (u + 0x7FFFu + ((u >> 16) & 1u)) >> 16;
    return (ushort)r;
}
__device__ __forceinline__ float lo_bf(uint v) {   // low bf16 -> f32
    union { uint u; float f; } c; c.u = v << 16; return c.f;
}
__device__ __forceinline__ float hi_bf(uint v) {   // high bf16 -> f32
    union { uint u; float f; } c; c.u = v & 0xffff0000u; return c.f;
}

// ---------------- graph prep ----------------

__global__ void zero_kernel(int4* __restrict__ p, int n16) {
    int i = blockIdx.x * blockDim.x + threadIdx.x;
    if (i < n16) p[i] = make_int4(0, 0, 0, 0);
}

// histogram + per-edge rank (order within its dst bucket)
__global__ void hist_kernel(const int* __restrict__ dst, int* __restrict__ deg,
                            int* __restrict__ rank, int E) {
    int e = blockIdx.x * blockDim.x + threadIdx.x;
    if (e < E) rank[e] = atomicAdd(&deg[dst[e]], 1);
}

// phase A: per-block (1024 elems) exclusive prescan + block sums
__global__ __launch_bounds__(256) void scan_blocks(const int* __restrict__ deg,
                                                   int* __restrict__ pre,
                                                   int* __restrict__ bsum, int n) {
    __shared__ int sh[256];
    int t = threadIdx.x;
    int base = blockIdx.x * 1024 + t * 4;
    int v0 = 0, v1 = 0, v2 = 0, v3 = 0;
    if (base + 3 < n) {
        int4 v = *reinterpret_cast<const int4*>(deg + base);
        v0 = v.x; v1 = v.y; v2 = v.z; v3 = v.w;
    } else {
        if (base     < n) v0 = deg[base];
        if (base + 1 < n) v1 = deg[base + 1];
        if (base + 2 < n) v2 = deg[base + 2];
        if (base + 3 < n) v3 = deg[base + 3];
    }
    int s = v0 + v1 + v2 + v3;
    sh[t] = s;
    __syncthreads();
    for (int off = 1; off < 256; off <<= 1) {
        int x = (t >= off) ? sh[t - off] : 0;
        __syncthreads();
        sh[t] += x;
        __syncthreads();
    }
    int excl = sh[t] - s;
    if (t == 255) bsum[blockIdx.x] = sh[255];
    if (base     < n) pre[base]     = excl;
    if (base + 1 < n) pre[base + 1] = excl + v0;
    if (base + 2 < n) pre[base + 2] = excl + v0 + v1;
    if (base + 3 < n) pre[base + 3] = excl + v0 + v1 + v2;
}

// phase B+C fused: every block re-scans bsum (<=64 entries) in wave 0, then adds
__global__ __launch_bounds__(256) void scan_add(
    const int* __restrict__ pre, const int* __restrict__ bsum,
    const int* __restrict__ deg,
    int* __restrict__ rowptr, float* __restrict__ dinv,
    int n, int E, int nb)
{
    __shared__ int sb[64];
    int t = threadIdx.x;
    if (t < 64) {
        int orig = (t < nb) ? bsum[t] : 0;
        int v = orig;
        for (int off = 1; off < 64; off <<= 1) {
            int u = __shfl_up(v, off);
            if (t >= off) v += u;
        }
        sb[t] = v - orig;   // exclusive
    }
    __syncthreads();
    int i = blockIdx.x * blockDim.x + t;
    if (i < n) {
        rowptr[i] = pre[i] + sb[i >> 10];
        int d = deg[i]; if (d < 1) d = 1;
        dinv[i] = rsqrtf((float)d);
    }
    if (i == 0) rowptr[n] = E;
}

// ---------------- phase2: fill CSR (no atomics) + conversions, one dispatch ----------------
// fill: col[rowptr[dst]+rank] = src, 4 edges/thread
// conv: featb = bf16(x); featbs = bf16(x*dinv) [N+1 rows, row N = 0]
//       W1t [128 cols][256 k]; W2ct [128 cols][128 k] (cols 0-63: y_top, 64-127: z2)

template <typename CT>
__global__ __launch_bounds__(256) void phase2_kernel(
    const int* __restrict__ src, const int* __restrict__ dst,
    const int* __restrict__ rowptr, const int* __restrict__ rank,
    CT* __restrict__ col, int E, int fillBlocks,
    const float* __restrict__ feats, const float* __restrict__ dinv,
    ushort* __restrict__ featb, ushort* __restrict__ featbs,
    ushort* __restrict__ z2s, int N, int nbF,
    const float* __restrict__ W1, ushort* __restrict__ W1t,
    const float* __restrict__ W2, ushort* __restrict__ W2ct)
{
    int b = blockIdx.x, t = threadIdx.x;
    if (b < fillBlocks) {
        int e0 = (b * 256 + t) * 4;
        if (e0 + 3 < E) {
            int4 d4 = *reinterpret_cast<const int4*>(dst + e0);
            int4 r4 = *reinterpret_cast<const int4*>(rank + e0);
            int4 s4 = *reinterpret_cast<const int4*>(src + e0);
            col[rowptr[d4.x] + r4.x] = (CT)s4.x;
            col[rowptr[d4.y] + r4.y] = (CT)s4.y;
            col[rowptr[d4.z] + r4.z] = (CT)s4.z;
            col[rowptr[d4.w] + r4.w] = (CT)s4.w;
        } else {
            for (int e = e0; e < E; ++e)
                col[rowptr[dst[e]] + rank[e]] = (CT)src[e];
        }
        return;
    }
    int b2 = b - fillBlocks;
    if (b2 < nbF) {
        size_t i4 = (size_t)b2 * 256 + t;         // float4 index
        if (i4 < (size_t)N * 32) {
            size_t i = i4 * 4;
            float4 v = *reinterpret_cast<const float4*>(feats + i);
            float dv = dinv[i >> 7];              // 4 consecutive floats share a node
            ushort4 o, os;
            o.x  = f2b1(v.x);      o.y  = f2b1(v.y);      o.z  = f2b1(v.z);      o.w  = f2b1(v.w);
            os.x = f2b1(v.x * dv); os.y = f2b1(v.y * dv); os.z = f2b1(v.z * dv); os.w = f2b1(v.w * dv);
            *reinterpret_cast<ushort4*>(featb  + i) = o;
            *reinterpret_cast<ushort4*>(featbs + i) = os;
        }
    } else if (b2 < nbF + 128) {
        if (b2 == nbF) {  // zero pad rows (row N of featbs: 128 ushorts; row N of z2s: 64)
            if (t < 32) *reinterpret_cast<uint2*>(featbs + (size_t)N * 128 + t * 4) = make_uint2(0, 0);
            else if (t < 48) *reinterpret_cast<uint2*>(z2s + (size_t)N * 64 + (t - 32) * 4) = make_uint2(0, 0);
        }
        int i = (b2 - nbF) * 256 + t;             // over 256*128
        int k = i >> 7, c = i & 127;
        W1t[(size_t)c * 256 + k] = f2b1(W1[i]);
    } else {
        int i = (b2 - nbF - 128) * 256 + t;       // over 128*128
        int c = i >> 7, k = i & 127;
        float v = (c < 64) ? W2[(size_t)k * 64 + c]
                           : W2[(size_t)(128 + k) * 64 + (c - 64)];
        W2ct[(size_t)c * 128 + k] = f2b1(v);
    }
}

// ---------------- aggregation layer 1: x1[n] = -dinv[n] * sum_e featbs[src_e] ----------------
// one wave/node; 16B/lane, 16 lanes cover a 256B row. 32-edge chunks: 8 static wide loads
// issued back-to-back (slots j*4+g), pads -> zero row N. High MLP, low VMEM instr count.

template <typename CT>
__global__ __launch_bounds__(256) void agg_sum128(
    const ushort* __restrict__ Xs, const int* __restrict__ rowptr,
    const CT* __restrict__ col, const float* __restrict__ dinv,
    ushort* __restrict__ X1, int nNodes)
{
    int wid  = (blockIdx.x * blockDim.x + threadIdx.x) >> 6;
    int lane = threadIdx.x & 63;
    if (wid >= nNodes) return;
    int n = __builtin_amdgcn_readfirstlane(wid);
    int e0 = rowptr[n], e1 = rowptr[n + 1];
    float sc = -dinv[n];
    const uint4* X4 = reinterpret_cast<const uint4*>(Xs);
    int d = lane & 15, g = lane >> 4;

    float a[8];
    #pragma unroll
    for (int i = 0; i < 8; ++i) a[i] = 0.f;

    for (int base = e0; base < e1; base += 32) {
        int idx = base + lane;                       // lanes 0..31 carry this chunk
        int cvl = (int)col[(idx < e1) ? idx : e0];
        int cv = (idx < e1) ? cvl : nNodes;          // pad -> zero row
        uint4 v[8];
        #pragma unroll
        for (int j = 0; j < 8; ++j) {
            int s = __shfl(cv, j * 4 + g);           // slots 0..31
            v[j] = X4[(uint)(s * 16 + d)];
        }
        #pragma unroll
        for (int j = 0; j < 8; ++j) {
            a[0] += lo_bf(v[j].x); a[1] += hi_bf(v[j].x);
            a[2] += lo_bf(v[j].y); a[3] += hi_bf(v[j].y);
            a[4] += lo_bf(v[j].z); a[5] += hi_bf(v[j].z);
            a[6] += lo_bf(v[j].w); a[7] += hi_bf(v[j].w);
        }
    }
    #pragma unroll
    for (int i = 0; i < 8; ++i) {
        a[i] += __shfl_xor(a[i], 16);
        a[i] += __shfl_xor(a[i], 32);
    }
    if (g == 0) {
        uint4 o;
        o.x = (uint)f2b1(a[0] * sc) | ((uint)f2b1(a[1] * sc) << 16);
        o.y = (uint)f2b1(a[2] * sc) | ((uint)f2b1(a[3] * sc) << 16);
        o.z = (uint)f2b1(a[4] * sc) | ((uint)f2b1(a[5] * sc) << 16);
        o.w = (uint)f2b1(a[6] * sc) | ((uint)f2b1(a[7] * sc) << 16);
        reinterpret_cast<uint4*>(X1)[(uint)(n * 16 + d)] = o;
    }
}

// ---------------- aggregation layer 2: out[n] += -dinv[n] * sum_e z2s[src_e] ----------------
// rows 128B: 8 lanes/row. 64-edge chunks: 8 static wide loads (slots j*8+g), pads -> zero row.

template <typename CT>
__global__ __launch_bounds__(256) void agg_sum64(
    const ushort* __restrict__ Zs, const int* __restrict__ rowptr,
    const CT* __restrict__ col, const float* __restrict__ dinv,
    float* __restrict__ Y, int nNodes)
{
    int wid  = (blockIdx.x * blockDim.x + threadIdx.x) >> 6;
    int lane = threadIdx.x & 63;
    if (wid >= nNodes) return;
    int n = __builtin_amdgcn_readfirstlane(wid);
    int e0 = rowptr[n], e1 = rowptr[n + 1];
    float sc = -dinv[n];
    const uint4* Z4 = reinterpret_cast<const uint4*>(Zs);
    int d = lane & 7, g = lane >> 3;

    float a[8];
    #pragma unroll
    for (int i = 0; i < 8; ++i) a[i] = 0.f;

    for (int base = e0; base < e1; base += 64) {
        int idx = base + lane;
        int cvl = (int)col[(idx < e1) ? idx : e0];
        int cv = (idx < e1) ? cvl : nNodes;          // pad -> zero row
        uint4 v[8];
        #pragma unroll
        for (int j = 0; j < 8; ++j) {
            int s = __shfl(cv, j * 8 + g);           // slots 0..63
            v[j] = Z4[(uint)(s * 8 + d)];
        }
        #pragma unroll
        for (int j = 0; j < 8; ++j) {
            a[0] += lo_bf(v[j].x); a[1] += hi_bf(v[j].x);
            a[2] += lo_bf(v[j].y); a[3] += hi_bf(v[j].y);
            a[4] += lo_bf(v[j].z); a[5] += hi_bf(v[j].z);
            a[6] += lo_bf(v[j].w); a[7] += hi_bf(v[j].w);
        }
    }
    #pragma unroll
    for (int i = 0; i < 8; ++i) {
        a[i] += __shfl_xor(a[i], 8);
        a[i] += __shfl_xor(a[i], 16);
        a[i] += __shfl_xor(a[i], 32);
    }
    if (g == 0) {
        // lane d covers fp32 cols [d*8, d*8+8) of the 64-col row: two float4s
        float4* Y4 = reinterpret_cast<float4*>(Y) + (uint)(n * 16 + d * 2);
        float4 y0 = Y4[0], y1 = Y4[1];
        y0.x += a[0] * sc; y0.y += a[1] * sc; y0.z += a[2] * sc; y0.w += a[3] * sc;
        y1.x += a[4] * sc; y1.y += a[5] * sc; y1.z += a[6] * sc; y1.w += a[7] * sc;
        Y4[0] = y0; Y4[1] = y1;
    }
}

// ---------------- MFMA GEMM layer 1: h1 = [XA | XB] @ W1 + b1 ----------------
// W1t staged in LDS (64KB, XOR-swizzled). Block = 4 waves x 32 nodes = 128 nodes.

__global__ __launch_bounds__(256) void gemm_mfma1(
    const ushort* __restrict__ XA, const ushort* __restrict__ XB,
    const ushort* __restrict__ Wt, const float* __restrict__ bias,
    ushort* __restrict__ Y, int nNodes)
{
    __shared__ ushort wlds[128 * 256];   // 64 KB: [col][512B row], swizzled
    int t = threadIdx.x;

    #pragma unroll
    for (int it = 0; it < 16; ++it) {
        int i = it * 256 + t;
        int c = i >> 5;                 // col 0..127
        int o = (i & 31) << 4;          // byte offset 0..496
        bf16x8 v = *reinterpret_cast<const bf16x8*>(Wt + ((size_t)c << 8) + (o >> 1));
        *reinterpret_cast<bf16x8*>((char*)wlds + ((size_t)c << 9) + (o ^ ((c & 7) << 4))) = v;
    }
    __syncthreads();

    int wave = t >> 6, lane = t & 63;
    int r16 = lane & 15, g = lane >> 4;
    int nodeBase = blockIdx.x * 128 + wave * 32;

    int arow0 = nodeBase + r16;       if (arow0 > nNodes - 1) arow0 = nNodes - 1;
    int arow1 = nodeBase + 16 + r16;  if (arow1 > nNodes - 1) arow1 = nNodes - 1;
    const ushort* pA0 = XA + (size_t)arow0 * 128;
    const ushort* pA1 = XA + (size_t)arow1 * 128;
    const ushort* pB0 = XB + (size_t)arow0 * 128;
    const ushort* pB1 = XB + (size_t)arow1 * 128;

    f32x4 acc0[8], acc1[8];
    #pragma unroll
    for (int i = 0; i < 8; ++i) { acc0[i] = f32x4{0,0,0,0}; acc1[i] = f32x4{0,0,0,0}; }

    #pragma unroll
    for (int kb = 0; kb < 8; ++kb) {
        int kk = (kb & 3) * 32 + g * 8;
        bf16x8 a0 = *reinterpret_cast<const bf16x8*>(((kb < 4) ? pA0 : pB0) + kk);
        bf16x8 a1 = *reinterpret_cast<const bf16x8*>(((kb < 4) ? pA1 : pB1) + kk);
        int o = kb * 64 + g * 16;
        #pragma unroll
        for (int ct = 0; ct < 8; ++ct) {
            int c = ct * 16 + r16;
            bf16x8 b = *reinterpret_cast<const bf16x8*>(
                (const char*)wlds + ((size_t)c << 9) + (o ^ ((c & 7) << 4)));
            acc0[ct] = __builtin_amdgcn_mfma_f32_16x16x32_bf16(a0, b, acc0[ct], 0, 0, 0);
            acc1[ct] = __builtin_amdgcn_mfma_f32_16x16x32_bf16(a1, b, acc1[ct], 0, 0, 0);
        }
    }

    #pragma unroll
    for (int ct = 0; ct < 8; ++ct) {
        float bv = bias[ct * 16 + r16];
        #pragma unroll
        for (int r = 0; r < 4; ++r) {
            int orow0 = nodeBase + g * 4 + r;
            int orow1 = orow0 + 16;
            if (orow0 < nNodes) Y[(size_t)orow0 * 128 + ct * 16 + r16] = f2b1(acc0[ct][r] + bv);
            if (orow1 < nNodes) Y[(size_t)orow1 * 128 + ct * 16 + r16] = f2b1(acc1[ct][r] + bv);
        }
    }
}

// ---------------- MFMA GEMM layer 2 fused: [y_top | z2s] = h1 @ W2c, K=128 ----------------
// cols 0-63 -> out fp32 (+bias); cols 64-127 -> z2s bf16, pre-scaled by dinv[row]

__global__ __launch_bounds__(256) void gemm_mfma2(
    const ushort* __restrict__ H1, const ushort* __restrict__ W2ct,
    const float* __restrict__ bias, const float* __restrict__ dinv,
    float* __restrict__ Yout, ushort* __restrict__ Z2, int nNodes)
{
    __shared__ ushort wlds[128 * 128];   // 32 KB: [col][256B row], swizzled
    int t = threadIdx.x;

    #pragma unroll
    for (int it = 0; it < 8; ++it) {
        int i = it * 256 + t;           // 2048 chunks of 16B
        int c = i >> 4;                 // col 0..127
        int o = (i & 15) << 4;          // byte offset 0..240
        bf16x8 v = *reinterpret_cast<const bf16x8*>(W2ct + ((size_t)c << 7) + (o >> 1));
        *reinterpret_cast<bf16x8*>((char*)wlds + ((size_t)c << 8) + (o ^ ((c & 7) << 4))) = v;
    }
    __syncthreads();

    int wave = t >> 6, lane = t & 63;
    int r16 = lane & 15, g = lane >> 4;
    int nodeBase = blockIdx.x * 128 + wave * 32;

    int arow0 = nodeBase + r16;       if (arow0 > nNodes - 1) arow0 = nNodes - 1;
    int arow1 = nodeBase + 16 + r16;  if (arow1 > nNodes - 1) arow1 = nNodes - 1;
    const ushort* p0 = H1 + (size_t)arow0 * 128;
    const ushort* p1 = H1 + (size_t)arow1 * 128;

    f32x4 acc0[8], acc1[8];
    #pragma unroll
    for (int i = 0; i < 8; ++i) { acc0[i] = f32x4{0,0,0,0}; acc1[i] = f32x4{0,0,0,0}; }

    #pragma unroll
    for (int kb = 0; kb < 4; ++kb) {
        int kk = kb * 32 + g * 8;
        bf16x8 a0 = *reinterpret_cast<const bf16x8*>(p0 + kk);
        bf16x8 a1 = *reinterpret_cast<const bf16x8*>(p1 + kk);
        int o = kb * 64 + g * 16;
        #pragma unroll
        for (int ct = 0; ct < 8; ++ct) {
            int c = ct * 16 + r16;
            bf16x8 b = *reinterpret_cast<const bf16x8*>(
                (const char*)wlds + ((size_t)c << 8) + (o ^ ((c & 7) << 4)));
            acc0[ct] = __builtin_amdgcn_mfma_f32_16x16x32_bf16(a0, b, acc0[ct], 0, 0, 0);
            acc1[ct] = __builtin_amdgcn_mfma_f32_16x16x32_bf16(a1, b, acc1[ct], 0, 0, 0);
        }
    }

    // per-output-row dinv for the z2s halves
    float dv0[4], dv1[4];
    #pragma unroll
    for (int r = 0; r < 4; ++r) {
        int o0 = nodeBase + g * 4 + r;      if (o0 > nNodes - 1) o0 = nNodes - 1;
        int o1 = nodeBase + 16 + g * 4 + r; if (o1 > nNodes - 1) o1 = nNodes - 1;
        dv0[r] = dinv[o0]; dv1[r] = dinv[o1];
    }

    #pragma unroll
    for (int ct = 0; ct < 8; ++ct) {
        float bv = (ct < 4) ? bias[ct * 16 + r16] : 0.f;
        #pragma unroll
        for (int r = 0; r < 4; ++r) {
            int orow0 = nodeBase + g * 4 + r;
            int orow1 = orow0 + 16;
            if (ct < 4) {
                if (orow0 < nNodes) Yout[(size_t)orow0 * 64 + ct * 16 + r16] = acc0[ct][r] + bv;
                if (orow1 < nNodes) Yout[(size_t)orow1 * 64 + ct * 16 + r16] = acc1[ct][r] + bv;
            } else {
                if (orow0 < nNodes) Z2[(size_t)orow0 * 64 + (ct - 4) * 16 + r16] = f2b1(acc0[ct][r] * dv0[r]);
                if (orow1 < nNodes) Z2[(size_t)orow1 * 64 + (ct - 4) * 16 + r16] = f2b1(acc1[ct][r] * dv1[r]);
            }
        }
    }
}

// ---------------- host ----------------

extern "C" void kernel_launch(void* const* d_in, const int* in_sizes, int n_in,
                              void* d_out, int out_size, void* d_ws, size_t ws_size,
                              hipStream_t stream)
{
    const float* feats = (const float*)d_in[0];
    const int*   src   = (const int*)d_in[1];
    const int*   dst   = (const int*)d_in[2];
    const float* W1    = (const float*)d_in[3];
    const float* b1    = (const float*)d_in[4];
    const float* W2    = (const float*)d_in[5];
    const float* b2    = (const float*)d_in[6];
    float* out = (float*)d_out;

    const int N = in_sizes[0] / IN_DIM;
    const int E = in_sizes[1];
    const int NB = (N + 1023) / 1024;

    char* ws = (char*)d_ws;
    size_t off = 0;
    int*    deg    = (int*)(ws + off);    off = align256(off + (size_t)N * 4);
    int*    rowptr = (int*)(ws + off);    off = align256(off + (size_t)(N + 1) * 4);
    int*    pre    = (int*)(ws + off);    off = align256(off + (size_t)N * 4);
    int*    bsum   = (int*)(ws + off);    off = align256(off + (size_t)64 * 4);
    int*    rank   = (int*)(ws + off);    off = align256(off + (size_t)E * 4);
    void*   colv   = (void*)(ws + off);   off = align256(off + (size_t)E * 4);
    float*  dinv   = (float*)(ws + off);  off = align256(off + (size_t)N * 4);
    ushort* featb  = (ushort*)(ws + off); off = align256(off + (size_t)N * 128 * 2);
    ushort* featbs = (ushort*)(ws + off); off = align256(off + (size_t)(N + 1) * 128 * 2);
    ushort* x1b    = (ushort*)(ws + off); off = align256(off + (size_t)N * 128 * 2);
    ushort* h1b    = (ushort*)(ws + off); off = align256(off + (size_t)N * 128 * 2);
    ushort* z2s    = (ushort*)(ws + off); off = align256(off + (size_t)(N + 1) * 64 * 2);
    ushort* W1t    = (ushort*)(ws + off); off = align256(off + (size_t)256 * 128 * 2);
    ushort* W2ct   = (ushort*)(ws + off); off = align256(off + (size_t)128 * 128 * 2);

    // graph prep
    const int n16 = (N + 3) / 4;
    zero_kernel<<<(n16 + 255) / 256, 256, 0, stream>>>((int4*)deg, n16);
    hist_kernel<<<(E + 255) / 256, 256, 0, stream>>>(dst, deg, rank, E);
    scan_blocks<<<NB, 256, 0, stream>>>(deg, pre, bsum, N);
    scan_add<<<(N + 255) / 256, 256, 0, stream>>>(pre, bsum, deg, rowptr, dinv, N, E, NB);

    // phase2: CSR fill + conversions (both depend only on scan_add)
    const bool small = (N <= 65535);
    const int fillBlocks = ((E + 3) / 4 + 255) / 256;
    const int nbF = (N * 32 + 255) / 256;
    const int p2Blocks = fillBlocks + nbF + 128 + 64;
    if (small)
        phase2_kernel<ushort><<<p2Blocks, 256, 0, stream>>>(
            src, dst, rowptr, rank, (ushort*)colv, E, fillBlocks,
            feats, dinv, featb, featbs, z2s, N, nbF, W1, W1t, W2, W2ct);
    else
        phase2_kernel<uint><<<p2Blocks, 256, 0, stream>>>(
            src, dst, rowptr, rank, (uint*)colv, E, fillBlocks,
            feats, dinv, featb, featbs, z2s, N, nbF, W1, W1t, W2, W2ct);

    const int aggBlocks = (N * 64 + 255) / 256;
    const int gemmBlocks = (N + 127) / 128;

    // layer 1: x1 = -dinv * sum featbs[src] ; h1 = [x | x1] @ W1 + b1
    if (small)
        agg_sum128<ushort><<<aggBlocks, 256, 0, stream>>>(featbs, rowptr, (const ushort*)colv, dinv, x1b, N);
    else
        agg_sum128<uint><<<aggBlocks, 256, 0, stream>>>(featbs, rowptr, (const uint*)colv, dinv, x1b, N);
    gemm_mfma1<<<gemmBlocks, 256, 0, stream>>>(featb, x1b, W1t, b1, h1b, N);

    // layer 2: [y_top | z2s] = h1 @ W2c ; out = y_top - dinv * sum z2s[src]
    gemm_mfma2<<<gemmBlocks, 256, 0, stream>>>(h1b, W2ct, b2, dinv, out, z2s, N);
    if (small)
        agg_sum64<ushort><<<aggBlocks, 256, 0, stream>>>(z2s, rowptr, (const ushort*)colv, dinv, out, N);
    else
        agg_sum64<uint><<<aggBlocks, 256, 0, stream>>>(z2s, rowptr, (const uint*)colv, dinv, out, N);
}

// Round 12
// 142.948 us; speedup vs baseline: 1.0620x; 1.0620x over previous
//
#include <hip/hip_runtime.h>

#define IN_DIM  128

typedef __bf16 bf16x8 __attribute__((ext_vector_type(8)));
typedef float  f32x4  __attribute__((ext_vector_type(4)));

static inline size_t align256(size_t x) { return (x + 255) & ~size_t(255); }

// ---------- bf16 helpers (RNE) ----------
__device__ __forceinline__ ushort f2b1(float f) {
    union { float f; uint u; } c; c.f = f;
    uint u = c.u;
    uint r = (u + 0x7FFFu + ((u >> 16) & 1u)) >> 16;
    return (ushort)r;
}
__device__ __forceinline__ float lo_bf(uint v) {   // low bf16 -> f32
    union { uint u; float f; } c; c.u = v << 16; return c.f;
}
__device__ __forceinline__ float hi_bf(uint v) {   // high bf16 -> f32
    union { uint u; float f; } c; c.u = v & 0xffff0000u; return c.f;
}

// ---------------- graph prep ----------------

__global__ void zero_kernel(int4* __restrict__ p, int n16) {
    int i = blockIdx.x * blockDim.x + threadIdx.x;
    if (i < n16) p[i] = make_int4(0, 0, 0, 0);
}

// histogram + per-edge rank (order within its dst bucket)
__global__ void hist_kernel(const int* __restrict__ dst, int* __restrict__ deg,
                            int* __restrict__ rank, int E) {
    int e = blockIdx.x * blockDim.x + threadIdx.x;
    if (e < E) rank[e] = atomicAdd(&deg[dst[e]], 1);
}

// phase A: per-block (1024 elems) exclusive prescan + block sums
__global__ __launch_bounds__(256) void scan_blocks(const int* __restrict__ deg,
                                                   int* __restrict__ pre,
                                                   int* __restrict__ bsum, int n) {
    __shared__ int sh[256];
    int t = threadIdx.x;
    int base = blockIdx.x * 1024 + t * 4;
    int v0 = 0, v1 = 0, v2 = 0, v3 = 0;
    if (base + 3 < n) {
        int4 v = *reinterpret_cast<const int4*>(deg + base);
        v0 = v.x; v1 = v.y; v2 = v.z; v3 = v.w;
    } else {
        if (base     < n) v0 = deg[base];
        if (base + 1 < n) v1 = deg[base + 1];
        if (base + 2 < n) v2 = deg[base + 2];
        if (base + 3 < n) v3 = deg[base + 3];
    }
    int s = v0 + v1 + v2 + v3;
    sh[t] = s;
    __syncthreads();
    for (int off = 1; off < 256; off <<= 1) {
        int x = (t >= off) ? sh[t - off] : 0;
        __syncthreads();
        sh[t] += x;
        __syncthreads();
    }
    int excl = sh[t] - s;
    if (t == 255) bsum[blockIdx.x] = sh[255];
    if (base     < n) pre[base]     = excl;
    if (base + 1 < n) pre[base + 1] = excl + v0;
    if (base + 2 < n) pre[base + 2] = excl + v0 + v1;
    if (base + 3 < n) pre[base + 3] = excl + v0 + v1 + v2;
}

// phase B+C fused: every block re-scans bsum (<=64 entries) in wave 0, then adds
__global__ __launch_bounds__(256) void scan_add(
    const int* __restrict__ pre, const int* __restrict__ bsum,
    const int* __restrict__ deg,
    int* __restrict__ rowptr, float* __restrict__ dinv,
    int n, int E, int nb)
{
    __shared__ int sb[64];
    int t = threadIdx.x;
    if (t < 64) {
        int orig = (t < nb) ? bsum[t] : 0;
        int v = orig;
        for (int off = 1; off < 64; off <<= 1) {
            int u = __shfl_up(v, off);
            if (t >= off) v += u;
        }
        sb[t] = v - orig;   // exclusive
    }
    __syncthreads();
    int i = blockIdx.x * blockDim.x + t;
    if (i < n) {
        rowptr[i] = pre[i] + sb[i >> 10];
        int d = deg[i]; if (d < 1) d = 1;
        dinv[i] = rsqrtf((float)d);
    }
    if (i == 0) rowptr[n] = E;
}

// ---------------- phase2: fill CSR (no atomics) + conversions, one dispatch ----------------
// fill: col[rowptr[dst]+rank] = src, 4 edges/thread
// conv: featb = bf16(x); featbs = bf16(x*dinv) [N+1 rows, row N = 0]
//       W1t [128 cols][256 k]; W2ct [128 cols][128 k] (cols 0-63: y_top, 64-127: z2)

template <typename CT>
__global__ __launch_bounds__(256) void phase2_kernel(
    const int* __restrict__ src, const int* __restrict__ dst,
    const int* __restrict__ rowptr, const int* __restrict__ rank,
    CT* __restrict__ col, int E, int fillBlocks,
    const float* __restrict__ feats, const float* __restrict__ dinv,
    ushort* __restrict__ featb, ushort* __restrict__ featbs,
    ushort* __restrict__ z2s, int N, int nbF,
    const float* __restrict__ W1, ushort* __restrict__ W1t,
    const float* __restrict__ W2, ushort* __restrict__ W2ct)
{
    int b = blockIdx.x, t = threadIdx.x;
    if (b < fillBlocks) {
        int e0 = (b * 256 + t) * 4;
        if (e0 + 3 < E) {
            int4 d4 = *reinterpret_cast<const int4*>(dst + e0);
            int4 r4 = *reinterpret_cast<const int4*>(rank + e0);
            int4 s4 = *reinterpret_cast<const int4*>(src + e0);
            col[rowptr[d4.x] + r4.x] = (CT)s4.x;
            col[rowptr[d4.y] + r4.y] = (CT)s4.y;
            col[rowptr[d4.z] + r4.z] = (CT)s4.z;
            col[rowptr[d4.w] + r4.w] = (CT)s4.w;
        } else {
            for (int e = e0; e < E; ++e)
                col[rowptr[dst[e]] + rank[e]] = (CT)src[e];
        }
        return;
    }
    int b2 = b - fillBlocks;
    if (b2 < nbF) {
        size_t i4 = (size_t)b2 * 256 + t;         // float4 index
        if (i4 < (size_t)N * 32) {
            size_t i = i4 * 4;
            float4 v = *reinterpret_cast<const float4*>(feats + i);
            float dv = dinv[i >> 7];              // 4 consecutive floats share a node
            ushort4 o, os;
            o.x  = f2b1(v.x);      o.y  = f2b1(v.y);      o.z  = f2b1(v.z);      o.w  = f2b1(v.w);
            os.x = f2b1(v.x * dv); os.y = f2b1(v.y * dv); os.z = f2b1(v.z * dv); os.w = f2b1(v.w * dv);
            *reinterpret_cast<ushort4*>(featb  + i) = o;
            *reinterpret_cast<ushort4*>(featbs + i) = os;
        }
    } else if (b2 < nbF + 128) {
        if (b2 == nbF) {  // zero pad rows (row N of featbs: 128 ushorts; row N of z2s: 64)
            if (t < 32) *reinterpret_cast<uint2*>(featbs + (size_t)N * 128 + t * 4) = make_uint2(0, 0);
            else if (t < 48) *reinterpret_cast<uint2*>(z2s + (size_t)N * 64 + (t - 32) * 4) = make_uint2(0, 0);
        }
        int i = (b2 - nbF) * 256 + t;             // over 256*128
        int k = i >> 7, c = i & 127;
        W1t[(size_t)c * 256 + k] = f2b1(W1[i]);
    } else {
        int i = (b2 - nbF - 128) * 256 + t;       // over 128*128
        int c = i >> 7, k = i & 127;
        float v = (c < 64) ? W2[(size_t)k * 64 + c]
                           : W2[(size_t)(128 + k) * 64 + (c - 64)];
        W2ct[(size_t)c * 128 + k] = f2b1(v);
    }
}

// ---------------- aggregation layer 1: x1[n] = -dinv[n] * sum_e featbs[src_e] ----------------
// TWO consecutive nodes per wave (adjacent CSR ranges). col slots for both in one load
// (lanes 0-31: node0, 32-63: node1); readlane -> scalar-address full-row gathers,
// 16+16 interleaved -> 32 contiguous 256B loads in flight. Pads -> zero row N.

template <typename CT>
__global__ __launch_bounds__(256) void agg_sum128(
    const ushort* __restrict__ Xs, const int* __restrict__ rowptr,
    const CT* __restrict__ col, const float* __restrict__ dinv,
    ushort* __restrict__ X1, int nNodes)
{
    int w    = (blockIdx.x * blockDim.x + threadIdx.x) >> 6;
    int lane = threadIdx.x & 63;
    int n0 = w * 2;
    if (n0 >= nNodes) return;
    n0 = __builtin_amdgcn_readfirstlane(n0);
    bool has1 = (n0 + 1) < nNodes;
    int e0a = rowptr[n0];
    int e1a = rowptr[n0 + 1];
    int e1b = has1 ? rowptr[n0 + 2] : e1a;
    float sca = -dinv[n0];
    float scb = -dinv[has1 ? n0 + 1 : n0];
    const uint* Xu = reinterpret_cast<const uint*>(Xs);

    float a0 = 0.f, a1 = 0.f, b0 = 0.f, b1 = 0.f;
    int basea = e0a, baseb = e1a;      // node1 edges start where node0's end
    while (basea < e1a || baseb < e1b) {
        int half = lane >> 5, sl = lane & 31;
        int idx = half ? (baseb + sl) : (basea + sl);
        int ee  = half ? e1b : e1a;
        bool okl = idx < ee;
        int cvl = (int)col[okl ? idx : 0];
        int cv  = okl ? cvl : nNodes;            // pad -> zero row
        int cnta = e1a - basea, cntb = e1b - baseb;
        {
            uint va[16], vb[16];
            #pragma unroll
            for (int j = 0; j < 16; ++j) {
                int s0 = __builtin_amdgcn_readlane(cv, j);
                int s1 = __builtin_amdgcn_readlane(cv, 32 + j);
                va[j] = Xu[(uint)(s0 * 64 + lane)];
                vb[j] = Xu[(uint)(s1 * 64 + lane)];
            }
            #pragma unroll
            for (int j = 0; j < 16; ++j) {
                a0 += lo_bf(va[j]); a1 += hi_bf(va[j]);
                b0 += lo_bf(vb[j]); b1 += hi_bf(vb[j]);
            }
        }
        if (cnta > 16 || cntb > 16) {
            uint va[16], vb[16];
            #pragma unroll
            for (int j = 0; j < 16; ++j) {
                int s0 = __builtin_amdgcn_readlane(cv, 16 + j);
                int s1 = __builtin_amdgcn_readlane(cv, 48 + j);
                va[j] = Xu[(uint)(s0 * 64 + lane)];
                vb[j] = Xu[(uint)(s1 * 64 + lane)];
            }
            #pragma unroll
            for (int j = 0; j < 16; ++j) {
                a0 += lo_bf(va[j]); a1 += hi_bf(va[j]);
                b0 += lo_bf(vb[j]); b1 += hi_bf(vb[j]);
            }
        }
        basea += 32; baseb += 32;
    }
    uint oA = (uint)f2b1(a0 * sca) | ((uint)f2b1(a1 * sca) << 16);
    reinterpret_cast<uint*>(X1)[(uint)(n0 * 64 + lane)] = oA;
    if (has1) {
        uint oB = (uint)f2b1(b0 * scb) | ((uint)f2b1(b1 * scb) << 16);
        reinterpret_cast<uint*>(X1)[(uint)((n0 + 1) * 64 + lane)] = oB;
    }
}

// ---------------- aggregation layer 2: out[n] += -dinv[n] * sum_e z2s[src_e] ----------------
// same dual-node scheme; rows are 64 bf16 -> ushort per lane (128B coalesced, scalar addr)

template <typename CT>
__global__ __launch_bounds__(256) void agg_sum64(
    const ushort* __restrict__ Zs, const int* __restrict__ rowptr,
    const CT* __restrict__ col, const float* __restrict__ dinv,
    float* __restrict__ Y, int nNodes)
{
    int w    = (blockIdx.x * blockDim.x + threadIdx.x) >> 6;
    int lane = threadIdx.x & 63;
    int n0 = w * 2;
    if (n0 >= nNodes) return;
    n0 = __builtin_amdgcn_readfirstlane(n0);
    bool has1 = (n0 + 1) < nNodes;
    int e0a = rowptr[n0];
    int e1a = rowptr[n0 + 1];
    int e1b = has1 ? rowptr[n0 + 2] : e1a;
    float sca = -dinv[n0];
    float scb = -dinv[has1 ? n0 + 1 : n0];

    float fa = 0.f, fb = 0.f;
    int basea = e0a, baseb = e1a;
    while (basea < e1a || baseb < e1b) {
        int half = lane >> 5, sl = lane & 31;
        int idx = half ? (baseb + sl) : (basea + sl);
        int ee  = half ? e1b : e1a;
        bool okl = idx < ee;
        int cvl = (int)col[okl ? idx : 0];
        int cv  = okl ? cvl : nNodes;            // pad -> zero row
        int cnta = e1a - basea, cntb = e1b - baseb;
        {
            ushort va[16], vb[16];
            #pragma unroll
            for (int j = 0; j < 16; ++j) {
                int s0 = __builtin_amdgcn_readlane(cv, j);
                int s1 = __builtin_amdgcn_readlane(cv, 32 + j);
                va[j] = Zs[(uint)(s0 * 64 + lane)];
                vb[j] = Zs[(uint)(s1 * 64 + lane)];
            }
            #pragma unroll
            for (int j = 0; j < 16; ++j) {
                fa += lo_bf((uint)va[j]);
                fb += lo_bf((uint)vb[j]);
            }
        }
        if (cnta > 16 || cntb > 16) {
            ushort va[16], vb[16];
            #pragma unroll
            for (int j = 0; j < 16; ++j) {
                int s0 = __builtin_amdgcn_readlane(cv, 16 + j);
                int s1 = __builtin_amdgcn_readlane(cv, 48 + j);
                va[j] = Zs[(uint)(s0 * 64 + lane)];
                vb[j] = Zs[(uint)(s1 * 64 + lane)];
            }
            #pragma unroll
            for (int j = 0; j < 16; ++j) {
                fa += lo_bf((uint)va[j]);
                fb += lo_bf((uint)vb[j]);
            }
        }
        basea += 32; baseb += 32;
    }
    Y[(uint)(n0 * 64 + lane)] += fa * sca;
    if (has1)
        Y[(uint)((n0 + 1) * 64 + lane)] += fb * scb;
}

// ---------------- MFMA GEMM layer 1: h1 = [XA | XB] @ W1 + b1 ----------------
// W1t staged in LDS (64KB, XOR-swizzled). Block = 4 waves x 32 nodes = 128 nodes.

__global__ __launch_bounds__(256) void gemm_mfma1(
    const ushort* __restrict__ XA, const ushort* __restrict__ XB,
    const ushort* __restrict__ Wt, const float* __restrict__ bias,
    ushort* __restrict__ Y, int nNodes)
{
    __shared__ ushort wlds[128 * 256];   // 64 KB: [col][512B row], swizzled
    int t = threadIdx.x;

    #pragma unroll
    for (int it = 0; it < 16; ++it) {
        int i = it * 256 + t;
        int c = i >> 5;                 // col 0..127
        int o = (i & 31) << 4;          // byte offset 0..496
        bf16x8 v = *reinterpret_cast<const bf16x8*>(Wt + ((size_t)c << 8) + (o >> 1));
        *reinterpret_cast<bf16x8*>((char*)wlds + ((size_t)c << 9) + (o ^ ((c & 7) << 4))) = v;
    }
    __syncthreads();

    int wave = t >> 6, lane = t & 63;
    int r16 = lane & 15, g = lane >> 4;
    int nodeBase = blockIdx.x * 128 + wave * 32;

    int arow0 = nodeBase + r16;       if (arow0 > nNodes - 1) arow0 = nNodes - 1;
    int arow1 = nodeBase + 16 + r16;  if (arow1 > nNodes - 1) arow1 = nNodes - 1;
    const ushort* pA0 = XA + (size_t)arow0 * 128;
    const ushort* pA1 = XA + (size_t)arow1 * 128;
    const ushort* pB0 = XB + (size_t)arow0 * 128;
    const ushort* pB1 = XB + (size_t)arow1 * 128;

    f32x4 acc0[8], acc1[8];
    #pragma unroll
    for (int i = 0; i < 8; ++i) { acc0[i] = f32x4{0,0,0,0}; acc1[i] = f32x4{0,0,0,0}; }

    #pragma unroll
    for (int kb = 0; kb < 8; ++kb) {
        int kk = (kb & 3) * 32 + g * 8;
        bf16x8 a0 = *reinterpret_cast<const bf16x8*>(((kb < 4) ? pA0 : pB0) + kk);
        bf16x8 a1 = *reinterpret_cast<const bf16x8*>(((kb < 4) ? pA1 : pB1) + kk);
        int o = kb * 64 + g * 16;
        #pragma unroll
        for (int ct = 0; ct < 8; ++ct) {
            int c = ct * 16 + r16;
            bf16x8 b = *reinterpret_cast<const bf16x8*>(
                (const char*)wlds + ((size_t)c << 9) + (o ^ ((c & 7) << 4)));
            acc0[ct] = __builtin_amdgcn_mfma_f32_16x16x32_bf16(a0, b, acc0[ct], 0, 0, 0);
            acc1[ct] = __builtin_amdgcn_mfma_f32_16x16x32_bf16(a1, b, acc1[ct], 0, 0, 0);
        }
    }

    #pragma unroll
    for (int ct = 0; ct < 8; ++ct) {
        float bv = bias[ct * 16 + r16];
        #pragma unroll
        for (int r = 0; r < 4; ++r) {
            int orow0 = nodeBase + g * 4 + r;
            int orow1 = orow0 + 16;
            if (orow0 < nNodes) Y[(size_t)orow0 * 128 + ct * 16 + r16] = f2b1(acc0[ct][r] + bv);
            if (orow1 < nNodes) Y[(size_t)orow1 * 128 + ct * 16 + r16] = f2b1(acc1[ct][r] + bv);
        }
    }
}

// ---------------- MFMA GEMM layer 2 fused: [y_top | z2s] = h1 @ W2c, K=128 ----------------
// cols 0-63 -> out fp32 (+bias); cols 64-127 -> z2s bf16, pre-scaled by dinv[row]

__global__ __launch_bounds__(256) void gemm_mfma2(
    const ushort* __restrict__ H1, const ushort* __restrict__ W2ct,
    const float* __restrict__ bias, const float* __restrict__ dinv,
    float* __restrict__ Yout, ushort* __restrict__ Z2, int nNodes)
{
    __shared__ ushort wlds[128 * 128];   // 32 KB: [col][256B row], swizzled
    int t = threadIdx.x;

    #pragma unroll
    for (int it = 0; it < 8; ++it) {
        int i = it * 256 + t;           // 2048 chunks of 16B
        int c = i >> 4;                 // col 0..127
        int o = (i & 15) << 4;          // byte offset 0..240
        bf16x8 v = *reinterpret_cast<const bf16x8*>(W2ct + ((size_t)c << 7) + (o >> 1));
        *reinterpret_cast<bf16x8*>((char*)wlds + ((size_t)c << 8) + (o ^ ((c & 7) << 4))) = v;
    }
    __syncthreads();

    int wave = t >> 6, lane = t & 63;
    int r16 = lane & 15, g = lane >> 4;
    int nodeBase = blockIdx.x * 128 + wave * 32;

    int arow0 = nodeBase + r16;       if (arow0 > nNodes - 1) arow0 = nNodes - 1;
    int arow1 = nodeBase + 16 + r16;  if (arow1 > nNodes - 1) arow1 = nNodes - 1;
    const ushort* p0 = H1 + (size_t)arow0 * 128;
    const ushort* p1 = H1 + (size_t)arow1 * 128;

    f32x4 acc0[8], acc1[8];
    #pragma unroll
    for (int i = 0; i < 8; ++i) { acc0[i] = f32x4{0,0,0,0}; acc1[i] = f32x4{0,0,0,0}; }

    #pragma unroll
    for (int kb = 0; kb < 4; ++kb) {
        int kk = kb * 32 + g * 8;
        bf16x8 a0 = *reinterpret_cast<const bf16x8*>(p0 + kk);
        bf16x8 a1 = *reinterpret_cast<const bf16x8*>(p1 + kk);
        int o = kb * 64 + g * 16;
        #pragma unroll
        for (int ct = 0; ct < 8; ++ct) {
            int c = ct * 16 + r16;
            bf16x8 b = *reinterpret_cast<const bf16x8*>(
                (const char*)wlds + ((size_t)c << 8) + (o ^ ((c & 7) << 4)));
            acc0[ct] = __builtin_amdgcn_mfma_f32_16x16x32_bf16(a0, b, acc0[ct], 0, 0, 0);
            acc1[ct] = __builtin_amdgcn_mfma_f32_16x16x32_bf16(a1, b, acc1[ct], 0, 0, 0);
        }
    }

    // per-output-row dinv for the z2s halves
    float dv0[4], dv1[4];
    #pragma unroll
    for (int r = 0; r < 4; ++r) {
        int o0 = nodeBase + g * 4 + r;      if (o0 > nNodes - 1) o0 = nNodes - 1;
        int o1 = nodeBase + 16 + g * 4 + r; if (o1 > nNodes - 1) o1 = nNodes - 1;
        dv0[r] = dinv[o0]; dv1[r] = dinv[o1];
    }

    #pragma unroll
    for (int ct = 0; ct < 8; ++ct) {
        float bv = (ct < 4) ? bias[ct * 16 + r16] : 0.f;
        #pragma unroll
        for (int r = 0; r < 4; ++r) {
            int orow0 = nodeBase + g * 4 + r;
            int orow1 = orow0 + 16;
            if (ct < 4) {
                if (orow0 < nNodes) Yout[(size_t)orow0 * 64 + ct * 16 + r16] = acc0[ct][r] + bv;
                if (orow1 < nNodes) Yout[(size_t)orow1 * 64 + ct * 16 + r16] = acc1[ct][r] + bv;
            } else {
                if (orow0 < nNodes) Z2[(size_t)orow0 * 64 + (ct - 4) * 16 + r16] = f2b1(acc0[ct][r] * dv0[r]);
                if (orow1 < nNodes) Z2[(size_t)orow1 * 64 + (ct - 4) * 16 + r16] = f2b1(acc1[ct][r] * dv1[r]);
            }
        }
    }
}

// ---------------- host ----------------

extern "C" void kernel_launch(void* const* d_in, const int* in_sizes, int n_in,
                              void* d_out, int out_size, void* d_ws, size_t ws_size,
                              hipStream_t stream)
{
    const float* feats = (const float*)d_in[0];
    const int*   src   = (const int*)d_in[1];
    const int*   dst   = (const int*)d_in[2];
    const float* W1    = (const float*)d_in[3];
    const float* b1    = (const float*)d_in[4];
    const float* W2    = (const float*)d_in[5];
    const float* b2    = (const float*)d_in[6];
    float* out = (float*)d_out;

    const int N = in_sizes[0] / IN_DIM;
    const int E = in_sizes[1];
    const int NB = (N + 1023) / 1024;

    char* ws = (char*)d_ws;
    size_t off = 0;
    int*    deg    = (int*)(ws + off);    off = align256(off + (size_t)N * 4);
    int*    rowptr = (int*)(ws + off);    off = align256(off + (size_t)(N + 1) * 4);
    int*    pre    = (int*)(ws + off);    off = align256(off + (size_t)N * 4);
    int*    bsum   = (int*)(ws + off);    off = align256(off + (size_t)64 * 4);
    int*    rank   = (int*)(ws + off);    off = align256(off + (size_t)E * 4);
    void*   colv   = (void*)(ws + off);   off = align256(off + (size_t)E * 4);
    float*  dinv   = (float*)(ws + off);  off = align256(off + (size_t)N * 4);
    ushort* featb  = (ushort*)(ws + off); off = align256(off + (size_t)N * 128 * 2);
    ushort* featbs = (ushort*)(ws + off); off = align256(off + (size_t)(N + 1) * 128 * 2);
    ushort* x1b    = (ushort*)(ws + off); off = align256(off + (size_t)N * 128 * 2);
    ushort* h1b    = (ushort*)(ws + off); off = align256(off + (size_t)N * 128 * 2);
    ushort* z2s    = (ushort*)(ws + off); off = align256(off + (size_t)(N + 1) * 64 * 2);
    ushort* W1t    = (ushort*)(ws + off); off = align256(off + (size_t)256 * 128 * 2);
    ushort* W2ct   = (ushort*)(ws + off); off = align256(off + (size_t)128 * 128 * 2);

    // graph prep
    const int n16 = (N + 3) / 4;
    zero_kernel<<<(n16 + 255) / 256, 256, 0, stream>>>((int4*)deg, n16);
    hist_kernel<<<(E + 255) / 256, 256, 0, stream>>>(dst, deg, rank, E);
    scan_blocks<<<NB, 256, 0, stream>>>(deg, pre, bsum, N);
    scan_add<<<(N + 255) / 256, 256, 0, stream>>>(pre, bsum, deg, rowptr, dinv, N, E, NB);

    // phase2: CSR fill + conversions (both depend only on scan_add)
    const bool small = (N <= 65535);
    const int fillBlocks = ((E + 3) / 4 + 255) / 256;
    const int nbF = (N * 32 + 255) / 256;
    const int p2Blocks = fillBlocks + nbF + 128 + 64;
    if (small)
        phase2_kernel<ushort><<<p2Blocks, 256, 0, stream>>>(
            src, dst, rowptr, rank, (ushort*)colv, E, fillBlocks,
            feats, dinv, featb, featbs, z2s, N, nbF, W1, W1t, W2, W2ct);
    else
        phase2_kernel<uint><<<p2Blocks, 256, 0, stream>>>(
            src, dst, rowptr, rank, (uint*)colv, E, fillBlocks,
            feats, dinv, featb, featbs, z2s, N, nbF, W1, W1t, W2, W2ct);

    const int nPairWaves = (N + 1) / 2;
    const int aggBlocks = (nPairWaves * 64 + 255) / 256;
    const int gemmBlocks = (N + 127) / 128;

    // layer 1: x1 = -dinv * sum featbs[src] ; h1 = [x | x1] @ W1 + b1
    if (small)
        agg_sum128<ushort><<<aggBlocks, 256, 0, stream>>>(featbs, rowptr, (const ushort*)colv, dinv, x1b, N);
    else
        agg_sum128<uint><<<aggBlocks, 256, 0, stream>>>(featbs, rowptr, (const uint*)colv, dinv, x1b, N);
    gemm_mfma1<<<gemmBlocks, 256, 0, stream>>>(featb, x1b, W1t, b1, h1b, N);

    // layer 2: [y_top | z2s] = h1 @ W2c ; out = y_top - dinv * sum z2s[src]
    gemm_mfma2<<<gemmBlocks, 256, 0, stream>>>(h1b, W2ct, b2, dinv, out, z2s, N);
    if (small)
        agg_sum64<ushort><<<aggBlocks, 256, 0, stream>>>(z2s, rowptr, (const ushort*)colv, dinv, out, N);
    else
        agg_sum64<uint><<<aggBlocks, 256, 0, stream>>>(z2s, rowptr, (const uint*)colv, dinv, out, N);
}